// Round 11
// baseline (279.862 us; speedup 1.0000x reference)
//
#include <hip/hip_runtime.h>
#include <hip/hip_bf16.h>

#define NN 4096
#define IC 128
#define OC 128
#define ED 16
#define EPB 128
#define NT 512
#define NSLOT 8
#define NBLK 256
#define NCPY 8

typedef __bf16 bf16x8 __attribute__((ext_vector_type(8)));
typedef float  f32x16 __attribute__((ext_vector_type(16)));

// raw barrier: drain LDS ops only; global loads/atomics stay in flight
#define BAR() do { asm volatile("s_waitcnt lgkmcnt(0)" ::: "memory"); \
    __builtin_amdgcn_s_barrier(); \
    __builtin_amdgcn_sched_barrier(0); } while (0)

__device__ __forceinline__ unsigned short bf16u(float f) {   // RNE f32->bf16
    unsigned int u = __float_as_uint(f);
    u = (u + 0x7FFFu + ((u >> 16) & 1u)) >> 16;
    return (unsigned short)u;
}
__device__ __forceinline__ float bf16tof(unsigned short h) {
    return __uint_as_float(((unsigned int)h) << 16);
}
__device__ __forceinline__ int swzk(int row) { return (row ^ (row >> 3)) & 7; }

// grid-wide barrier: sense-reversal, device-scope atomics.
// Safe: 88KB LDS/block -> exactly 1 block/CU, grid=256=CU count -> all
// blocks co-resident. __threadfence = agent-scope fence (L2 wb/inv on gfx950).
__device__ __forceinline__ void gsync(int* cnt, int* gen) {
    __syncthreads();
    if (threadIdx.x == 0) {
        __threadfence();   // release: make this block's writes device-visible
        const int my = __hip_atomic_load(gen, __ATOMIC_SEQ_CST,
                                         __HIP_MEMORY_SCOPE_AGENT);
        const int arrived = __hip_atomic_fetch_add(cnt, 1, __ATOMIC_SEQ_CST,
                                                   __HIP_MEMORY_SCOPE_AGENT);
        if (arrived == NBLK - 1) {
            __hip_atomic_store(cnt, 0, __ATOMIC_SEQ_CST,
                               __HIP_MEMORY_SCOPE_AGENT);
            __hip_atomic_fetch_add(gen, 1, __ATOMIC_SEQ_CST,
                                   __HIP_MEMORY_SCOPE_AGENT);
        } else {
            while (__hip_atomic_load(gen, __ATOMIC_SEQ_CST,
                                     __HIP_MEMORY_SCOPE_AGENT) == my) {
                __builtin_amdgcn_s_sleep(8);
            }
        }
        __threadfence();   // acquire: invalidate local caches
    }
    __syncthreads();
}

// ONE persistent kernel: zero-out + xw1b + hist -> scanA -> scanB ->
// scatter -> edge phase (k_edge7 body). 4 internal grid syncs replace
// 4 launch boundaries + full-device drains + the 1-block-scan bubble.
__global__ __launch_bounds__(NT, 2) void k_all(
    const float* __restrict__ x, const int* __restrict__ eidx,
    const float* __restrict__ eattr, const float* __restrict__ W1,
    const float* __restrict__ b1, const float* __restrict__ W2,
    const float* __restrict__ b2, float* __restrict__ out,
    float* __restrict__ xw1b, int* __restrict__ hist8,
    int* __restrict__ cursor8, int* __restrict__ blocksum,
    int* __restrict__ gbar, int2* __restrict__ csr, int E)
{
    extern __shared__ char smem[];
    const int t   = threadIdx.x;
    const int bid = blockIdx.x;

    // ================= phase 0: zero out + xw1b slice + hist ============
    ((float4*)out)[bid * NT + t] = make_float4(0.f, 0.f, 0.f, 0.f);

    {   // xw1b rows [bid*16, bid*16+16): thread -> (row = t>>5, 4 channels)
        const int row = bid * 16 + (t >> 5);
        const int c4  = (t & 31) * 4;
        float4 a = make_float4(b1[c4], b1[c4 + 1], b1[c4 + 2], b1[c4 + 3]);
        const float4* xr = (const float4*)(x + (size_t)row * IC);
        #pragma unroll 8
        for (int k4 = 0; k4 < 32; ++k4) {
            const float4 xv = xr[k4];
            const float4 w0 = *(const float4*)(W1 + (size_t)(k4 * 4 + 0) * OC + c4);
            const float4 w1v = *(const float4*)(W1 + (size_t)(k4 * 4 + 1) * OC + c4);
            const float4 w2v = *(const float4*)(W1 + (size_t)(k4 * 4 + 2) * OC + c4);
            const float4 w3v = *(const float4*)(W1 + (size_t)(k4 * 4 + 3) * OC + c4);
            a.x = fmaf(xv.x, w0.x, a.x); a.y = fmaf(xv.x, w0.y, a.y);
            a.z = fmaf(xv.x, w0.z, a.z); a.w = fmaf(xv.x, w0.w, a.w);
            a.x = fmaf(xv.y, w1v.x, a.x); a.y = fmaf(xv.y, w1v.y, a.y);
            a.z = fmaf(xv.y, w1v.z, a.z); a.w = fmaf(xv.y, w1v.w, a.w);
            a.x = fmaf(xv.z, w2v.x, a.x); a.y = fmaf(xv.z, w2v.y, a.y);
            a.z = fmaf(xv.z, w2v.z, a.z); a.w = fmaf(xv.z, w2v.w, a.w);
            a.x = fmaf(xv.w, w3v.x, a.x); a.y = fmaf(xv.w, w3v.y, a.y);
            a.z = fmaf(xv.w, w3v.z, a.z); a.w = fmaf(xv.w, w3v.w, a.w);
        }
        *(float4*)(xw1b + (size_t)row * OC + c4) = a;
    }

    {   // hist: edges [bid*1024, +1024), copy = bid&7 (hist8 pre-zeroed)
        const int k  = bid & (NCPY - 1);
        const int e0 = bid * 1024;
        #pragma unroll
        for (int j = 0; j < 2; ++j)
            atomicAdd(&hist8[k * 4096 + eidx[E + e0 + t + j * NT]], 1);
    }
    gsync(gbar, gbar + 1);

    // ================= phase 1: scan-A (16 bins per block) ==============
    int* sbl = (int*)smem;          // [16]
    int* loc = sbl + 16;            // [16]  (persists to phase 2)
    int* bsl = sbl + 32;            // [256] (phase 2)
    if (t < 16) {
        const int bin = bid * 16 + t;
        int sb = 0;
        #pragma unroll
        for (int k = 0; k < NCPY; ++k) sb += hist8[k * 4096 + bin];
        sbl[t] = sb;
    }
    __syncthreads();
    if (t == 0) {
        int a = 0;
        #pragma unroll
        for (int j = 0; j < 16; ++j) { loc[j] = a; a += sbl[j]; }
        blocksum[bid] = a;
    }
    gsync(gbar, gbar + 1);

    // ================= phase 2: scan-B (cursor init) ====================
    if (t < 256) bsl[t] = blocksum[t];
    __syncthreads();
    if (t == 0) {
        int a = 0;
        for (int j = 0; j < bid; ++j) a += bsl[j];
        sbl[0] = a;    // base for this block's bins
    }
    __syncthreads();
    if (t < 16) {
        const int bin = bid * 16 + t;
        int off = sbl[0] + loc[t];
        #pragma unroll
        for (int k = 0; k < NCPY; ++k) {
            cursor8[k * 4096 + bin] = off;
            off += hist8[k * 4096 + bin];
        }
    }
    gsync(gbar, gbar + 1);

    // ================= phase 3: scatter =================================
    {
        const int k  = bid & (NCPY - 1);
        const int e0 = bid * 1024;
        #pragma unroll
        for (int j = 0; j < 2; ++j) {
            const int e   = e0 + t + j * NT;
            const int row = eidx[e];
            const int col = eidx[E + e];
            const int pos = atomicAdd(&cursor8[k * 4096 + col], 1);
            csr[pos] = make_int2(row, col);
        }
    }
    gsync(gbar, gbar + 1);

    // ================= phase 4: edge phase (k_edge7 body) ===============
    char*   const h1hi = smem;                      // 32KB bf16 [128e][128k] swz
    char*   const h1lo = smem + 32768;              // 32KB
    float4* const eaL  = (float4*)(smem + 65536);   // [512] swz (8KB)
    float4* const w1L  = (float4*)(smem + 73728);   // [512] (8KB)
    float*  const lacc = (float*)(smem + 81920);    // [8][128] (4KB)
    int*    const srowL = (int*)(smem + 86016);     // [2][128]
    int*    const scolL = srowL + 256;              // [2][128]

    const int l   = t & 63;
    const int wid = t >> 6;
    const int cg  = t & 15, eg = t >> 4;
    const int c0  = cg << 3, e0 = eg << 2;
    const int sz  = (eg >> 1) & 3;
    const int em  = t >> 2, q = t & 3;
    const int esz = (em >> 3) & 3;

    const int ntl = wid & 3;
    const int mh  = wid >> 2;
    const int lm  = l & 31;
    const int hi  = l >> 5;
    const int c2  = ntl * 32 + lm;

    w1L[t] = ((const float4*)(W1 + (size_t)IC * OC))[t];

    bf16x8 w2h[8], w2l[8];
    #pragma unroll
    for (int s = 0; s < 8; ++s) {
        union { unsigned short us[8]; bf16x8 v; } Uh, Ul;
        #pragma unroll
        for (int j = 0; j < 8; ++j) {
            const float w = W2[(size_t)(s * 16 + hi * 8 + j) * OC + c2];
            const unsigned short h = bf16u(w);
            Uh.us[j] = h;
            Ul.us[j] = bf16u(w - bf16tof(h));
        }
        w2h[s] = Uh.v; w2l[s] = Ul.v;
    }
    const float b2s = b2[c2];

    lacc[t] = 0.f; lacc[t + NT] = 0.f;

    const int nper = (E / EPB) / NBLK;      // 8
    const int ibb  = bid * nper;

    if (t < EPB) {
        const int2 rc = csr[(size_t)ibb * EPB + t];
        srowL[t] = rc.x;
        scolL[t] = rc.y;
    }
    __syncthreads();

    float4 pA;
    {
        const int r = srowL[em], c = scolL[em];
        pA = ((const float4*)(eattr + ((size_t)r * NN + c) * ED))[q];
    }
    int2 pidx;
    {
        const int ibn = (nper > 1) ? 1 : 0;
        pidx = (t < EPB) ? csr[(size_t)(ibb + ibn) * EPB + t] : make_int2(0, 0);
    }

    int cur = 0;
    for (int ii = 0; ii < nper; ++ii) {
        const int nxt = cur ^ 1;

        BAR();

        if (t < EPB) { srowL[nxt * 128 + t] = pidx.x; scolL[nxt * 128 + t] = pidx.y; }
        eaL[(em * 4 + q) ^ esz] = pA;
        float4 xa[4], xb[4];
        #pragma unroll
        for (int ri = 0; ri < 4; ++ri) {
            const int row = srowL[cur * 128 + e0 + ri];
            const float4* p = (const float4*)(xw1b + (size_t)row * OC + c0);
            xa[ri] = p[0]; xb[ri] = p[1];
        }
        BAR();

        float4 ha[4], hb[4];
        #pragma unroll
        for (int ri = 0; ri < 4; ++ri) { ha[ri] = xa[ri]; hb[ri] = xb[ri]; }
        #pragma unroll
        for (int dc = 0; dc < 4; ++dc) {
            float4 ev[4];
            #pragma unroll
            for (int ri = 0; ri < 4; ++ri)
                ev[ri] = eaL[((e0 + ri) * 4 + dc) ^ sz];
            #pragma unroll
            for (int dd = 0; dd < 4; ++dd) {
                const int d = dc * 4 + dd;
                const float4 wA = w1L[d * 32 + cg * 2];
                const float4 wB = w1L[d * 32 + cg * 2 + 1];
                #pragma unroll
                for (int ri = 0; ri < 4; ++ri) {
                    const float evd = (dd == 0) ? ev[ri].x : (dd == 1) ? ev[ri].y
                                     : (dd == 2) ? ev[ri].z : ev[ri].w;
                    ha[ri].x = fmaf(evd, wA.x, ha[ri].x);
                    ha[ri].y = fmaf(evd, wA.y, ha[ri].y);
                    ha[ri].z = fmaf(evd, wA.z, ha[ri].z);
                    ha[ri].w = fmaf(evd, wA.w, ha[ri].w);
                    hb[ri].x = fmaf(evd, wB.x, hb[ri].x);
                    hb[ri].y = fmaf(evd, wB.y, hb[ri].y);
                    hb[ri].z = fmaf(evd, wB.z, hb[ri].z);
                    hb[ri].w = fmaf(evd, wB.w, hb[ri].w);
                }
            }
        }
        #pragma unroll
        for (int ri = 0; ri < 4; ++ri) {
            const int row = e0 + ri;
            float v[8] = { ha[ri].x, ha[ri].y, ha[ri].z, ha[ri].w,
                           hb[ri].x, hb[ri].y, hb[ri].z, hb[ri].w };
            union { unsigned short us[8]; uint4 qv; } Hh, Hl;
            #pragma unroll
            for (int j = 0; j < 8; ++j) {
                const float f = fmaxf(v[j], 0.f);
                const unsigned short h = bf16u(f);
                Hh.us[j] = h;
                Hl.us[j] = bf16u(f - bf16tof(h));
            }
            const int boff = (cg * 16) ^ (swzk(row) << 4);
            *(uint4*)(h1hi + row * 256 + boff) = Hh.qv;
            *(uint4*)(h1lo + row * 256 + boff) = Hl.qv;
        }
        {
            const int r = srowL[nxt * 128 + em], c = scolL[nxt * 128 + em];
            pA = ((const float4*)(eattr + ((size_t)r * NN + c) * ED))[q];
        }
        {
            const int iin = (ii + 2 < nper) ? (ii + 2) : (nper - 1);
            pidx = (t < EPB) ? csr[(size_t)(ibb + iin) * EPB + t] : make_int2(0, 0);
        }
        BAR();

        f32x16 acc0 = (f32x16)(0.0f);
        f32x16 acc1 = (f32x16)(0.0f);
        const int arow0 = (mh * 2 + 0) * 32 + lm;
        const int arow1 = (mh * 2 + 1) * 32 + lm;
        const int ak0 = swzk(arow0) << 4;
        const int ak1 = swzk(arow1) << 4;
        #pragma unroll
        for (int s = 0; s < 8; ++s) {
            const int kb = s * 32 + hi * 16;
            const bf16x8 aH0 = *(const bf16x8*)(h1hi + arow0 * 256 + (kb ^ ak0));
            const bf16x8 aL0 = *(const bf16x8*)(h1lo + arow0 * 256 + (kb ^ ak0));
            const bf16x8 aH1 = *(const bf16x8*)(h1hi + arow1 * 256 + (kb ^ ak1));
            const bf16x8 aL1 = *(const bf16x8*)(h1lo + arow1 * 256 + (kb ^ ak1));
            acc0 = __builtin_amdgcn_mfma_f32_32x32x16_bf16(aH0, w2h[s], acc0, 0, 0, 0);
            acc1 = __builtin_amdgcn_mfma_f32_32x32x16_bf16(aH1, w2h[s], acc1, 0, 0, 0);
            acc0 = __builtin_amdgcn_mfma_f32_32x32x16_bf16(aL0, w2h[s], acc0, 0, 0, 0);
            acc1 = __builtin_amdgcn_mfma_f32_32x32x16_bf16(aL1, w2h[s], acc1, 0, 0, 0);
            acc0 = __builtin_amdgcn_mfma_f32_32x32x16_bf16(aH0, w2l[s], acc0, 0, 0, 0);
            acc1 = __builtin_amdgcn_mfma_f32_32x32x16_bf16(aH1, w2l[s], acc1, 0, 0, 0);
        }

        const int colbase = scolL[cur * 128];
        #pragma unroll
        for (int p = 0; p < 2; ++p) {
            const int mbase = (mh * 2 + p) * 32 + 4 * hi;
            #pragma unroll
            for (int g = 0; g < 4; ++g) {
                const int eb = mbase + 8 * g;
                float sv;
                {
                    const float a0 = (p == 0) ? acc0[4 * g] : acc1[4 * g];
                    sv = fmaxf(a0 + b2s, 0.f);
                }
                int ccur = scolL[cur * 128 + eb];
                #pragma unroll
                for (int j = 1; j < 4; ++j) {
                    const float aj = (p == 0) ? acc0[4 * g + j] : acc1[4 * g + j];
                    const float v = fmaxf(aj + b2s, 0.f);
                    const int c = scolL[cur * 128 + eb + j];
                    if (c == ccur) {
                        sv += v;
                    } else {
                        const int slot = ccur - colbase;
                        if (slot < NSLOT) {
                            if (sv != 0.f) atomicAdd(&lacc[slot * OC + c2], sv);
                        } else {
                            if (sv != 0.f) atomicAdd(&out[(size_t)ccur * OC + c2], sv);
                        }
                        ccur = c; sv = v;
                    }
                }
                const int slot = ccur - colbase;
                if (slot < NSLOT) {
                    if (sv != 0.f) atomicAdd(&lacc[slot * OC + c2], sv);
                } else {
                    if (sv != 0.f) atomicAdd(&out[(size_t)ccur * OC + c2], sv);
                }
            }
        }
        BAR();

        int span = scolL[cur * 128 + 127] - colbase + 1;
        if (span > NSLOT) span = NSLOT;
        for (int idx = t; idx < span * OC; idx += NT) {
            const float v = lacc[idx];
            lacc[idx] = 0.f;
            if (v != 0.f)
                atomicAdd(&out[(size_t)(colbase + (idx >> 7)) * OC + (idx & 127)], v);
        }
        cur = nxt;
    }
}

#define LDS_BYTES 88064

extern "C" void kernel_launch(void* const* d_in, const int* in_sizes, int n_in,
                              void* d_out, int out_size, void* d_ws, size_t ws_size,
                              hipStream_t stream) {
    const float* x    = (const float*)d_in[0];
    const int*   eidx = (const int*)d_in[1];
    const float* ea   = (const float*)d_in[2];
    const float* W1   = (const float*)d_in[3];
    const float* b1   = (const float*)d_in[4];
    const float* W2   = (const float*)d_in[5];
    const float* b2   = (const float*)d_in[6];
    float* out = (float*)d_out;

    const int E = in_sizes[1] / 2;

    char* ws = (char*)d_ws;
    float* xw1b     = (float*)ws;                      // 2 MB
    int*   hist8    = (int*)(ws + 2097152);            // 128 KB
    int*   cursor8  = (int*)(ws + 2228224);            // 128 KB
    int*   blocksum = (int*)(ws + 2359296);            // 1 KB
    int*   gbar     = (int*)(ws + 2360320);            // 64 B
    int2*  csr      = (int2*)(ws + 2621440);           // 2 MB

    // zero hist8 + cursor8 + blocksum + gbar (263,232 B) each call
    hipMemsetAsync(ws + 2097152, 0, 263232, stream);

    hipFuncSetAttribute(reinterpret_cast<const void*>(k_all),
                        hipFuncAttributeMaxDynamicSharedMemorySize, LDS_BYTES);
    k_all<<<NBLK, NT, LDS_BYTES, stream>>>(x, eidx, ea, W1, b1, W2, b2,
                                           out, xw1b, hist8, cursor8,
                                           blocksum, gbar, csr, E);
}

// Round 13
// 140.875 us; speedup vs baseline: 1.9866x; 1.9866x over previous
//
#include <hip/hip_runtime.h>
#include <hip/hip_bf16.h>

#define NN 4096
#define IC 128
#define OC 128
#define ED 16
#define EPB 64
#define NT 256
#define NSLOT 8
#define NBLK 512
#define NCPY 8

typedef __bf16 bf16x8 __attribute__((ext_vector_type(8)));
typedef float  f32x16 __attribute__((ext_vector_type(16)));

// raw barrier: drain LDS ops only; global loads/atomics stay in flight
#define BAR() do { asm volatile("s_waitcnt lgkmcnt(0)" ::: "memory"); \
    __builtin_amdgcn_s_barrier(); \
    __builtin_amdgcn_sched_barrier(0); } while (0)

__device__ __forceinline__ unsigned short bf16u(float f) {   // RNE f32->bf16
    unsigned int u = __float_as_uint(f);
    u = (u + 0x7FFFu + ((u >> 16) & 1u)) >> 16;
    return (unsigned short)u;
}
__device__ __forceinline__ float bf16tof(unsigned short h) {
    return __uint_as_float(((unsigned int)h) << 16);
}
__device__ __forceinline__ int swzk(int row) { return (row ^ (row >> 3)) & 7; }

// ---- Phase 1: xw1b = x@W1[:128]+b1; zero out; fused 8-replica hist ------
// Replica mapping MUST match k_scatter: edge e -> copy (e>>8)&7
// (round-12 bug: used (e>>9)&7 here -> cursor segments overran -> fault).
__global__ __launch_bounds__(128) void k_xw1(
    const float* __restrict__ x, const float* __restrict__ W1,
    const float* __restrict__ b1, const int* __restrict__ eidx,
    float* __restrict__ xw1b, float* __restrict__ out,
    int* __restrict__ hist8, int E)
{
    __shared__ float xs[8][IC];
    const int t = threadIdx.x;
    const int r0 = blockIdx.x * 8;
    #pragma unroll
    for (int r = 0; r < 8; ++r) xs[r][t] = x[(size_t)(r0 + r) * IC + t];

    const float4 z = make_float4(0.f, 0.f, 0.f, 0.f);
    float4* o4 = (float4*)out;
    o4[blockIdx.x * 256 + t]       = z;
    o4[blockIdx.x * 256 + 128 + t] = z;

    // fused hist: 512 edges per block; copy = (e>>8)&7 == (2*bid + (j>>1))&7
    {
        const int e0 = blockIdx.x * 512;
        #pragma unroll
        for (int j = 0; j < 4; ++j) {
            const int k = (2 * blockIdx.x + (j >> 1)) & (NCPY - 1);
            atomicAdd(&hist8[k * 4096 + eidx[E + e0 + t + j * 128]], 1);
        }
    }

    __syncthreads();
    float acc[8];
    const float bb = b1[t];
    #pragma unroll
    for (int r = 0; r < 8; ++r) acc[r] = bb;
    #pragma unroll 4
    for (int k = 0; k < IC; ++k) {
        const float w = W1[(size_t)k * OC + t];
        #pragma unroll
        for (int r = 0; r < 8; ++r) acc[r] = fmaf(xs[r][k], w, acc[r]);
    }
    #pragma unroll
    for (int r = 0; r < 8; ++r) xw1b[(size_t)(r0 + r) * OC + t] = acc[r];
}

// -------- scan + scatter (8-replica, round-10-proven) ---------------------
__global__ __launch_bounds__(256) void k_scan(
    const int* __restrict__ hist8, int* __restrict__ cursor8)
{
    __shared__ int tot[256];
    __shared__ int base[256];
    const int t = threadIdx.x;
    int loc[16];
    int s = 0;
    #pragma unroll
    for (int j = 0; j < 16; ++j) {
        const int b = t * 16 + j;
        int sb = 0;
        #pragma unroll
        for (int k = 0; k < NCPY; ++k) sb += hist8[k * 4096 + b];
        loc[j] = s; s += sb;
    }
    tot[t] = s;
    __syncthreads();
    if (t == 0) {
        int a = 0;
        for (int i = 0; i < 256; ++i) { base[i] = a; a += tot[i]; }
    }
    __syncthreads();
    const int a = base[t];
    #pragma unroll
    for (int j = 0; j < 16; ++j) {
        const int b = t * 16 + j;
        int off = a + loc[j];
        #pragma unroll
        for (int k = 0; k < NCPY; ++k) {
            cursor8[k * 4096 + b] = off;
            off += hist8[k * 4096 + b];
        }
    }
}

__global__ void k_scatter(const int* __restrict__ eidx, int* __restrict__ cursor8,
                          int2* __restrict__ csr, int E) {
    const int i = blockIdx.x * blockDim.x + threadIdx.x;
    const int k = blockIdx.x & (NCPY - 1);   // == (i>>8)&7, blockDim=256
    if (i < E) {
        const int row = eidx[i];
        const int col = eidx[E + i];
        const int pos = atomicAdd(&cursor8[k * 4096 + col], 1);
        csr[pos] = make_int2(row, col);
    }
}

// ---------------- Phase 2: 64-edge batches, 2 blocks/CU -------------------
// 512 blocks x 256 threads (4 waves), 50KB LDS -> TWO independent blocks
// per CU: when one block sits at a barrier or in an MFMA phase, the other
// block's DS/VALU work fills the pipe (breaks the single-block lockstep).
// Same per-edge math as round 8: f32 layer-1, 3-term bf16-split 32x32x16
// MFMA layer-2 with W2 in registers, sorted-run-combine + lacc epilogue.
__global__ __launch_bounds__(NT, 2) void k_edge8(
    const int2* __restrict__ csr, const float* __restrict__ eattr,
    const float* __restrict__ xw1b, const float* __restrict__ W1,
    const float* __restrict__ W2, const float* __restrict__ b2,
    float* __restrict__ out, int E)
{
    extern __shared__ char smem[];
    char*   const h1hi = smem;                      // 16KB bf16 [64e][128k] swz
    char*   const h1lo = smem + 16384;              // 16KB
    float4* const eaL  = (float4*)(smem + 32768);   // [256] swz (4KB)
    float4* const w1L  = (float4*)(smem + 36864);   // [512] (8KB)
    float*  const lacc = (float*)(smem + 45056);    // [8][128] (4KB)
    int*    const srowL = (int*)(smem + 49152);     // [2][64]
    int*    const scolL = srowL + 128;              // [2][64]

    const int t   = threadIdx.x;
    const int l   = t & 63;
    const int wid = t >> 6;                 // 4 waves
    const int cg  = t & 15, eg = t >> 4;    // layer-1 tile: 4e x 8c; eg 0..15
    const int c0  = cg << 3, e0 = eg << 2;
    const int sz  = (eg >> 1) & 3;          // per-edge swizzle key ((e>>3)&3)
    const int em  = t >> 2, q = t & 3;      // ea gather: 4 threads/edge
    const int esz = (em >> 3) & 3;

    const int lm  = l & 31;
    const int hi  = l >> 5;
    const int c2  = wid * 32 + lm;          // this lane's output channel

    w1L[t]       = ((const float4*)(W1 + (size_t)IC * OC))[t];
    w1L[t + NT]  = ((const float4*)(W1 + (size_t)IC * OC))[t + NT];

    // W2 -> register hi/lo fragments (batch-invariant, 64 VGPR)
    bf16x8 w2h[8], w2l[8];
    #pragma unroll
    for (int s = 0; s < 8; ++s) {
        union { unsigned short us[8]; bf16x8 v; } Uh, Ul;
        #pragma unroll
        for (int j = 0; j < 8; ++j) {
            const float w = W2[(size_t)(s * 16 + hi * 8 + j) * OC + c2];
            const unsigned short h = bf16u(w);
            Uh.us[j] = h;
            Ul.us[j] = bf16u(w - bf16tof(h));
        }
        w2h[s] = Uh.v; w2l[s] = Ul.v;
    }
    const float b2s = b2[c2];

    #pragma unroll
    for (int i = 0; i < 4; ++i) lacc[t + NT * i] = 0.f;

    const int nper = (E / EPB) / NBLK;      // 8 batches per block
    const int ibb  = blockIdx.x * nper;

    if (t < EPB) {
        const int2 rc = csr[(size_t)ibb * EPB + t];
        srowL[t] = rc.x;
        scolL[t] = rc.y;
    }
    __syncthreads();

    float4 pA;                               // ea prefetch (batch cur)
    {
        const int r = srowL[em], c = scolL[em];
        pA = ((const float4*)(eattr + ((size_t)r * NN + c) * ED))[q];
    }
    int2 pidx;                               // idx prefetch (batch cur+1)
    {
        const int ibn = (nper > 1) ? 1 : 0;
        pidx = (t < EPB) ? csr[(size_t)(ibb + ibn) * EPB + t] : make_int2(0, 0);
    }

    int cur = 0;
    for (int ii = 0; ii < nper; ++ii) {
        const int nxt = cur ^ 1;

        BAR();  // prev flush done; srow[nxt] free

        if (t < EPB) { srowL[nxt * EPB + t] = pidx.x; scolL[nxt * EPB + t] = pidx.y; }
        eaL[(em * 4 + q) ^ esz] = pA;
        float4 xa[4], xb[4];
        #pragma unroll
        for (int ri = 0; ri < 4; ++ri) {
            const int row = srowL[cur * EPB + e0 + ri];
            const float4* p = (const float4*)(xw1b + (size_t)row * OC + c0);
            xa[ri] = p[0]; xb[ri] = p[1];
        }
        BAR();  // eaL + srow[nxt] visible

        // layer 1 (f32): 4e x 8c per thread
        float4 ha[4], hb[4];
        #pragma unroll
        for (int ri = 0; ri < 4; ++ri) { ha[ri] = xa[ri]; hb[ri] = xb[ri]; }
        #pragma unroll
        for (int dc = 0; dc < 4; ++dc) {
            float4 ev[4];
            #pragma unroll
            for (int ri = 0; ri < 4; ++ri)
                ev[ri] = eaL[((e0 + ri) * 4 + dc) ^ sz];
            #pragma unroll
            for (int dd = 0; dd < 4; ++dd) {
                const int d = dc * 4 + dd;
                const float4 wA = w1L[d * 32 + cg * 2];
                const float4 wB = w1L[d * 32 + cg * 2 + 1];
                #pragma unroll
                for (int ri = 0; ri < 4; ++ri) {
                    const float evd = (dd == 0) ? ev[ri].x : (dd == 1) ? ev[ri].y
                                     : (dd == 2) ? ev[ri].z : ev[ri].w;
                    ha[ri].x = fmaf(evd, wA.x, ha[ri].x);
                    ha[ri].y = fmaf(evd, wA.y, ha[ri].y);
                    ha[ri].z = fmaf(evd, wA.z, ha[ri].z);
                    ha[ri].w = fmaf(evd, wA.w, ha[ri].w);
                    hb[ri].x = fmaf(evd, wB.x, hb[ri].x);
                    hb[ri].y = fmaf(evd, wB.y, hb[ri].y);
                    hb[ri].z = fmaf(evd, wB.z, hb[ri].z);
                    hb[ri].w = fmaf(evd, wB.w, hb[ri].w);
                }
            }
        }
        // relu + bf16 hi/lo split -> h1 planes
        #pragma unroll
        for (int ri = 0; ri < 4; ++ri) {
            const int row = e0 + ri;
            float v[8] = { ha[ri].x, ha[ri].y, ha[ri].z, ha[ri].w,
                           hb[ri].x, hb[ri].y, hb[ri].z, hb[ri].w };
            union { unsigned short us[8]; uint4 qv; } Hh, Hl;
            #pragma unroll
            for (int j = 0; j < 8; ++j) {
                const float f = fmaxf(v[j], 0.f);
                const unsigned short h = bf16u(f);
                Hh.us[j] = h;
                Hl.us[j] = bf16u(f - bf16tof(h));
            }
            const int boff = (cg * 16) ^ (swzk(row) << 4);
            *(uint4*)(h1hi + row * 256 + boff) = Hh.qv;
            *(uint4*)(h1lo + row * 256 + boff) = Hl.qv;
        }
        // prefetch next batch ea + idx(ii+2)
        {
            const int r = srowL[nxt * EPB + em], c = scolL[nxt * EPB + em];
            pA = ((const float4*)(eattr + ((size_t)r * NN + c) * ED))[q];
        }
        {
            const int iin = (ii + 2 < nper) ? (ii + 2) : (nper - 1);
            pidx = (t < EPB) ? csr[(size_t)(ibb + iin) * EPB + t] : make_int2(0, 0);
        }
        BAR();  // h1 planes visible

        // layer 2: 32x32x16 MFMA, 3-term split, B from registers.
        // wave = one 32-chan n-tile x both 32-edge m-tiles.
        f32x16 acc0 = (f32x16)(0.0f);
        f32x16 acc1 = (f32x16)(0.0f);
        const int arow0 = lm;
        const int arow1 = 32 + lm;
        const int ak0 = swzk(arow0) << 4;
        const int ak1 = swzk(arow1) << 4;
        #pragma unroll
        for (int s = 0; s < 8; ++s) {
            const int kb = s * 32 + hi * 16;
            const bf16x8 aH0 = *(const bf16x8*)(h1hi + arow0 * 256 + (kb ^ ak0));
            const bf16x8 aL0 = *(const bf16x8*)(h1lo + arow0 * 256 + (kb ^ ak0));
            const bf16x8 aH1 = *(const bf16x8*)(h1hi + arow1 * 256 + (kb ^ ak1));
            const bf16x8 aL1 = *(const bf16x8*)(h1lo + arow1 * 256 + (kb ^ ak1));
            acc0 = __builtin_amdgcn_mfma_f32_32x32x16_bf16(aH0, w2h[s], acc0, 0, 0, 0);
            acc1 = __builtin_amdgcn_mfma_f32_32x32x16_bf16(aH1, w2h[s], acc1, 0, 0, 0);
            acc0 = __builtin_amdgcn_mfma_f32_32x32x16_bf16(aL0, w2h[s], acc0, 0, 0, 0);
            acc1 = __builtin_amdgcn_mfma_f32_32x32x16_bf16(aL1, w2h[s], acc1, 0, 0, 0);
            acc0 = __builtin_amdgcn_mfma_f32_32x32x16_bf16(aH0, w2l[s], acc0, 0, 0, 0);
            acc1 = __builtin_amdgcn_mfma_f32_32x32x16_bf16(aH1, w2l[s], acc1, 0, 0, 0);
        }

        // epilogue: C layout col=lane&31, row=(reg&3)+8*(reg>>2)+4*(lane>>5)
        const int colbase = scolL[cur * EPB];
        #pragma unroll
        for (int p = 0; p < 2; ++p) {
            const int mbase = p * 32 + 4 * hi;
            #pragma unroll
            for (int g = 0; g < 4; ++g) {
                const int eb = mbase + 8 * g;
                float sv;
                {
                    const float a0 = (p == 0) ? acc0[4 * g] : acc1[4 * g];
                    sv = fmaxf(a0 + b2s, 0.f);
                }
                int ccur = scolL[cur * EPB + eb];
                #pragma unroll
                for (int j = 1; j < 4; ++j) {
                    const float aj = (p == 0) ? acc0[4 * g + j] : acc1[4 * g + j];
                    const float v = fmaxf(aj + b2s, 0.f);
                    const int c = scolL[cur * EPB + eb + j];
                    if (c == ccur) {
                        sv += v;
                    } else {
                        const int slot = ccur - colbase;
                        if (slot < NSLOT) {
                            if (sv != 0.f) atomicAdd(&lacc[slot * OC + c2], sv);
                        } else {
                            if (sv != 0.f) atomicAdd(&out[(size_t)ccur * OC + c2], sv);
                        }
                        ccur = c; sv = v;
                    }
                }
                const int slot = ccur - colbase;
                if (slot < NSLOT) {
                    if (sv != 0.f) atomicAdd(&lacc[slot * OC + c2], sv);
                } else {
                    if (sv != 0.f) atomicAdd(&out[(size_t)ccur * OC + c2], sv);
                }
            }
        }
        BAR();  // lacc complete

        int span = scolL[cur * EPB + EPB - 1] - colbase + 1;
        if (span > NSLOT) span = NSLOT;
        for (int idx = t; idx < span * OC; idx += NT) {
            const float v = lacc[idx];
            lacc[idx] = 0.f;
            if (v != 0.f)
                atomicAdd(&out[(size_t)(colbase + (idx >> 7)) * OC + (idx & 127)], v);
        }
        cur = nxt;
    }
}

#define LDS_BYTES 50176

extern "C" void kernel_launch(void* const* d_in, const int* in_sizes, int n_in,
                              void* d_out, int out_size, void* d_ws, size_t ws_size,
                              hipStream_t stream) {
    const float* x    = (const float*)d_in[0];
    const int*   eidx = (const int*)d_in[1];
    const float* ea   = (const float*)d_in[2];
    const float* W1   = (const float*)d_in[3];
    const float* b1   = (const float*)d_in[4];
    const float* W2   = (const float*)d_in[5];
    const float* b2   = (const float*)d_in[6];
    float* out = (float*)d_out;

    const int E = in_sizes[1] / 2;

    char* ws = (char*)d_ws;
    float* xw1b    = (float*)ws;                         // 2 MB
    int*   hist8   = (int*)(ws + 2097152);               // 128 KB
    int*   cursor8 = (int*)(ws + 2097152 + 131072);      // 128 KB
    int2*  csr     = (int2*)(ws + 2097152 + 262144);     // 2 MB

    hipMemsetAsync(hist8, 0, 131072, stream);
    k_xw1<<<NN / 8, 128, 0, stream>>>(x, W1, b1, eidx, xw1b, out, hist8, E);
    k_scan<<<1, 256, 0, stream>>>(hist8, cursor8);
    k_scatter<<<(E + 255) / 256, 256, 0, stream>>>(eidx, cursor8, csr, E);

    hipFuncSetAttribute(reinterpret_cast<const void*>(k_edge8),
                        hipFuncAttributeMaxDynamicSharedMemorySize, LDS_BYTES);
    k_edge8<<<NBLK, NT, LDS_BYTES, stream>>>(csr, ea, xw1b, W1, W2, b2, out, E);
}

// Round 14
// 139.129 us; speedup vs baseline: 2.0115x; 1.0126x over previous
//
#include <hip/hip_runtime.h>
#include <hip/hip_bf16.h>

#define NN 4096
#define IC 128
#define OC 128
#define ED 16
#define EPB 64
#define NT 256
#define NSLOT 8
#define NBLK 512
#define NCPY 8

typedef __bf16 bf16x8 __attribute__((ext_vector_type(8)));
typedef float  f32x16 __attribute__((ext_vector_type(16)));

// raw barrier: drain LDS ops only; global loads/atomics stay in flight
#define BAR() do { asm volatile("s_waitcnt lgkmcnt(0)" ::: "memory"); \
    __builtin_amdgcn_s_barrier(); \
    __builtin_amdgcn_sched_barrier(0); } while (0)

__device__ __forceinline__ unsigned short bf16u(float f) {   // RNE f32->bf16
    unsigned int u = __float_as_uint(f);
    u = (u + 0x7FFFu + ((u >> 16) & 1u)) >> 16;
    return (unsigned short)u;
}
__device__ __forceinline__ float bf16tof(unsigned short h) {
    return __uint_as_float(((unsigned int)h) << 16);
}
__device__ __forceinline__ int swzk(int row) { return (row ^ (row >> 3)) & 7; }

// ---- Phase 1: xw1b = x@W1[:128]+b1; zero out; fused 8-replica hist ------
// Replica mapping matches k_scatter: edge e -> copy (e>>8)&7.
__global__ __launch_bounds__(128) void k_xw1(
    const float* __restrict__ x, const float* __restrict__ W1,
    const float* __restrict__ b1, const int* __restrict__ eidx,
    float* __restrict__ xw1b, float* __restrict__ out,
    int* __restrict__ hist8, int E)
{
    __shared__ float xs[8][IC];
    const int t = threadIdx.x;
    const int r0 = blockIdx.x * 8;
    #pragma unroll
    for (int r = 0; r < 8; ++r) xs[r][t] = x[(size_t)(r0 + r) * IC + t];

    const float4 z = make_float4(0.f, 0.f, 0.f, 0.f);
    float4* o4 = (float4*)out;
    o4[blockIdx.x * 256 + t]       = z;
    o4[blockIdx.x * 256 + 128 + t] = z;

    {
        const int e0 = blockIdx.x * 512;
        #pragma unroll
        for (int j = 0; j < 4; ++j) {
            const int k = (2 * blockIdx.x + (j >> 1)) & (NCPY - 1);
            atomicAdd(&hist8[k * 4096 + eidx[E + e0 + t + j * 128]], 1);
        }
    }

    __syncthreads();
    float acc[8];
    const float bb = b1[t];
    #pragma unroll
    for (int r = 0; r < 8; ++r) acc[r] = bb;
    #pragma unroll 4
    for (int k = 0; k < IC; ++k) {
        const float w = W1[(size_t)k * OC + t];
        #pragma unroll
        for (int r = 0; r < 8; ++r) acc[r] = fmaf(xs[r][k], w, acc[r]);
    }
    #pragma unroll
    for (int r = 0; r < 8; ++r) xw1b[(size_t)(r0 + r) * OC + t] = acc[r];
}

// -------- scan + scatter (8-replica, round-10-proven) ---------------------
__global__ __launch_bounds__(256) void k_scan(
    const int* __restrict__ hist8, int* __restrict__ cursor8)
{
    __shared__ int tot[256];
    __shared__ int base[256];
    const int t = threadIdx.x;
    int loc[16];
    int s = 0;
    #pragma unroll
    for (int j = 0; j < 16; ++j) {
        const int b = t * 16 + j;
        int sb = 0;
        #pragma unroll
        for (int k = 0; k < NCPY; ++k) sb += hist8[k * 4096 + b];
        loc[j] = s; s += sb;
    }
    tot[t] = s;
    __syncthreads();
    if (t == 0) {
        int a = 0;
        for (int i = 0; i < 256; ++i) { base[i] = a; a += tot[i]; }
    }
    __syncthreads();
    const int a = base[t];
    #pragma unroll
    for (int j = 0; j < 16; ++j) {
        const int b = t * 16 + j;
        int off = a + loc[j];
        #pragma unroll
        for (int k = 0; k < NCPY; ++k) {
            cursor8[k * 4096 + b] = off;
            off += hist8[k * 4096 + b];
        }
    }
}

__global__ void k_scatter(const int* __restrict__ eidx, int* __restrict__ cursor8,
                          int2* __restrict__ csr, int E) {
    const int i = blockIdx.x * blockDim.x + threadIdx.x;
    const int k = blockIdx.x & (NCPY - 1);
    if (i < E) {
        const int row = eidx[i];
        const int col = eidx[E + i];
        const int pos = atomicAdd(&cursor8[k * 4096 + col], 1);
        csr[pos] = make_int2(row, col);
    }
}

// ---------------- Phase 2: 2-barrier batch loop (was 4) -------------------
// R13 shell (EPB=64, NT=256, 2 blocks/CU) with the batch pipeline
// restructured per m233: eaL double-buffered, idx quad-buffered, all LDS
// staging writes moved INTO the compute phases so they ride the two
// existing barriers. Per batch: PhaseA{L1+h1+idx-write+prefetch-issue}
// BAR PhaseB{L2 MFMA+epilogue+eaL-write} BAR {flush}. Math identical.
__global__ __launch_bounds__(NT, 2) void k_edge9(
    const int2* __restrict__ csr, const float* __restrict__ eattr,
    const float* __restrict__ xw1b, const float* __restrict__ W1,
    const float* __restrict__ W2, const float* __restrict__ b2,
    float* __restrict__ out, int E)
{
    extern __shared__ char smem[];
    char*   const h1hi = smem;                      // 16KB bf16 [64e][128k] swz
    char*   const h1lo = smem + 16384;              // 16KB
    float4* const eaL  = (float4*)(smem + 32768);   // [2][256] swz (8KB)
    float4* const w1L  = (float4*)(smem + 40960);   // [512] (8KB)
    float*  const lacc = (float*)(smem + 49152);    // [8][128] (4KB)
    int*    const srowL = (int*)(smem + 53248);     // [4][64]
    int*    const scolL = srowL + 256;              // [4][64]

    const int t   = threadIdx.x;
    const int l   = t & 63;
    const int wid = t >> 6;                 // 4 waves
    const int cg  = t & 15, eg = t >> 4;    // layer-1 tile: 4e x 8c; eg 0..15
    const int c0  = cg << 3, e0 = eg << 2;
    const int sz  = (eg >> 1) & 3;          // per-edge swizzle key ((e>>3)&3)
    const int em  = t >> 2, q = t & 3;      // ea gather: 4 threads/edge
    const int esz = (em >> 3) & 3;

    const int lm  = l & 31;
    const int hi  = l >> 5;
    const int c2  = wid * 32 + lm;          // this lane's output channel

    w1L[t]       = ((const float4*)(W1 + (size_t)IC * OC))[t];
    w1L[t + NT]  = ((const float4*)(W1 + (size_t)IC * OC))[t + NT];

    // W2 -> register hi/lo fragments (batch-invariant, 64 VGPR)
    bf16x8 w2h[8], w2l[8];
    #pragma unroll
    for (int s = 0; s < 8; ++s) {
        union { unsigned short us[8]; bf16x8 v; } Uh, Ul;
        #pragma unroll
        for (int j = 0; j < 8; ++j) {
            const float w = W2[(size_t)(s * 16 + hi * 8 + j) * OC + c2];
            const unsigned short h = bf16u(w);
            Uh.us[j] = h;
            Ul.us[j] = bf16u(w - bf16tof(h));
        }
        w2h[s] = Uh.v; w2l[s] = Ul.v;
    }
    const float b2s = b2[c2];

    #pragma unroll
    for (int i = 0; i < 4; ++i) lacc[t + NT * i] = 0.f;

    const int nper = (E / EPB) / NBLK;      // 8 batches per block
    const int ibb  = blockIdx.x * nper;

    // ---- prologue: idx(0),idx(1) -> LDS; ea(0) -> eaL[0]; xw(0) -> regs;
    //      pidx = idx(2) ----
    if (t < EPB) {
        const int2 r0v = csr[(size_t)ibb * EPB + t];
        srowL[t] = r0v.x; scolL[t] = r0v.y;
        const int ib1 = (nper > 1) ? 1 : 0;
        const int2 r1v = csr[(size_t)(ibb + ib1) * EPB + t];
        srowL[64 + t] = r1v.x; scolL[64 + t] = r1v.y;
    }
    __syncthreads();

    float4 pA;
    {
        const int r = srowL[em], c = scolL[em];
        pA = ((const float4*)(eattr + ((size_t)r * NN + c) * ED))[q];
    }
    eaL[(em * 4 + q) ^ esz] = pA;           // eaL buffer 0 = batch 0
    float4 xa[4], xb[4];
    #pragma unroll
    for (int ri = 0; ri < 4; ++ri) {
        const int row = srowL[e0 + ri];
        const float4* p = (const float4*)(xw1b + (size_t)row * OC + c0);
        xa[ri] = p[0]; xb[ri] = p[1];
    }
    int2 pidx;
    {
        const int ib2 = (nper > 2) ? 2 : (nper - 1);
        pidx = (t < EPB) ? csr[(size_t)(ibb + ib2) * EPB + t] : make_int2(0, 0);
    }
    __syncthreads();                        // eaL[0] visible

    for (int ii = 0; ii < nper; ++ii) {
        const int cb  = ii & 1;             // ea buffer of batch ii
        const int ib4 = ii & 3;             // idx buffer of batch ii

        // ======== Phase A: layer-1 + staging writes + prefetch issue =====
        float4 ha[4], hb[4];
        #pragma unroll
        for (int ri = 0; ri < 4; ++ri) { ha[ri] = xa[ri]; hb[ri] = xb[ri]; }
        #pragma unroll
        for (int dc = 0; dc < 4; ++dc) {
            float4 ev[4];
            #pragma unroll
            for (int ri = 0; ri < 4; ++ri)
                ev[ri] = eaL[cb * 256 + ((((e0 + ri) * 4 + dc)) ^ sz)];
            #pragma unroll
            for (int dd = 0; dd < 4; ++dd) {
                const int d = dc * 4 + dd;
                const float4 wA = w1L[d * 32 + cg * 2];
                const float4 wB = w1L[d * 32 + cg * 2 + 1];
                #pragma unroll
                for (int ri = 0; ri < 4; ++ri) {
                    const float evd = (dd == 0) ? ev[ri].x : (dd == 1) ? ev[ri].y
                                     : (dd == 2) ? ev[ri].z : ev[ri].w;
                    ha[ri].x = fmaf(evd, wA.x, ha[ri].x);
                    ha[ri].y = fmaf(evd, wA.y, ha[ri].y);
                    ha[ri].z = fmaf(evd, wA.z, ha[ri].z);
                    ha[ri].w = fmaf(evd, wA.w, ha[ri].w);
                    hb[ri].x = fmaf(evd, wB.x, hb[ri].x);
                    hb[ri].y = fmaf(evd, wB.y, hb[ri].y);
                    hb[ri].z = fmaf(evd, wB.z, hb[ri].z);
                    hb[ri].w = fmaf(evd, wB.w, hb[ri].w);
                }
            }
        }
        // relu + bf16 hi/lo split -> h1 planes
        #pragma unroll
        for (int ri = 0; ri < 4; ++ri) {
            const int row = e0 + ri;
            float v[8] = { ha[ri].x, ha[ri].y, ha[ri].z, ha[ri].w,
                           hb[ri].x, hb[ri].y, hb[ri].z, hb[ri].w };
            union { unsigned short us[8]; uint4 qv; } Hh, Hl;
            #pragma unroll
            for (int j = 0; j < 8; ++j) {
                const float f = fmaxf(v[j], 0.f);
                const unsigned short h = bf16u(f);
                Hh.us[j] = h;
                Hl.us[j] = bf16u(f - bf16tof(h));
            }
            const int boff = (cg * 16) ^ (swzk(row) << 4);
            *(uint4*)(h1hi + row * 256 + boff) = Hh.qv;
            *(uint4*)(h1lo + row * 256 + boff) = Hl.qv;
        }
        // idx(ii+2) -> LDS buffer (ii+2)&3 (from regs; no global round-trip)
        if (t < EPB) {
            srowL[((ii + 2) & 3) * 64 + t] = pidx.x;
            scolL[((ii + 2) & 3) * 64 + t] = pidx.y;
        }
        // issue prefetches for batch ii+1 (idx in buffer (ii+1)&3)
        {
            const int jn = (ii + 1) & 3;
            const int r = srowL[jn * 64 + em], c = scolL[jn * 64 + em];
            pA = ((const float4*)(eattr + ((size_t)r * NN + c) * ED))[q];
            #pragma unroll
            for (int ri = 0; ri < 4; ++ri) {
                const int row = srowL[jn * 64 + e0 + ri];
                const float4* p = (const float4*)(xw1b + (size_t)row * OC + c0);
                xa[ri] = p[0]; xb[ri] = p[1];
            }
        }
        // issue csr load idx(ii+3)
        {
            const int iin = (ii + 3 < nper) ? (ii + 3) : (nper - 1);
            pidx = (t < EPB) ? csr[(size_t)(ibb + iin) * EPB + t] : make_int2(0, 0);
        }
        BAR();  // BAR-1: h1 + idx(ii+2) visible; prefetches stay in flight

        // ======== Phase B: layer-2 MFMA + epilogue + eaL(ii+1) write =====
        f32x16 acc0 = (f32x16)(0.0f);
        f32x16 acc1 = (f32x16)(0.0f);
        const int arow0 = lm;
        const int arow1 = 32 + lm;
        const int ak0 = swzk(arow0) << 4;
        const int ak1 = swzk(arow1) << 4;
        #pragma unroll
        for (int s = 0; s < 8; ++s) {
            const int kb = s * 32 + hi * 16;
            const bf16x8 aH0 = *(const bf16x8*)(h1hi + arow0 * 256 + (kb ^ ak0));
            const bf16x8 aL0 = *(const bf16x8*)(h1lo + arow0 * 256 + (kb ^ ak0));
            const bf16x8 aH1 = *(const bf16x8*)(h1hi + arow1 * 256 + (kb ^ ak1));
            const bf16x8 aL1 = *(const bf16x8*)(h1lo + arow1 * 256 + (kb ^ ak1));
            acc0 = __builtin_amdgcn_mfma_f32_32x32x16_bf16(aH0, w2h[s], acc0, 0, 0, 0);
            acc1 = __builtin_amdgcn_mfma_f32_32x32x16_bf16(aH1, w2h[s], acc1, 0, 0, 0);
            acc0 = __builtin_amdgcn_mfma_f32_32x32x16_bf16(aL0, w2h[s], acc0, 0, 0, 0);
            acc1 = __builtin_amdgcn_mfma_f32_32x32x16_bf16(aL1, w2h[s], acc1, 0, 0, 0);
            acc0 = __builtin_amdgcn_mfma_f32_32x32x16_bf16(aH0, w2l[s], acc0, 0, 0, 0);
            acc1 = __builtin_amdgcn_mfma_f32_32x32x16_bf16(aH1, w2l[s], acc1, 0, 0, 0);
        }

        // epilogue: C layout col=lane&31, row=(reg&3)+8*(reg>>2)+4*(lane>>5)
        const int colbase = scolL[ib4 * 64];
        #pragma unroll
        for (int p = 0; p < 2; ++p) {
            const int mbase = p * 32 + 4 * hi;
            #pragma unroll
            for (int g = 0; g < 4; ++g) {
                const int eb = mbase + 8 * g;
                float sv;
                {
                    const float a0 = (p == 0) ? acc0[4 * g] : acc1[4 * g];
                    sv = fmaxf(a0 + b2s, 0.f);
                }
                int ccur = scolL[ib4 * 64 + eb];
                #pragma unroll
                for (int j = 1; j < 4; ++j) {
                    const float aj = (p == 0) ? acc0[4 * g + j] : acc1[4 * g + j];
                    const float v = fmaxf(aj + b2s, 0.f);
                    const int c = scolL[ib4 * 64 + eb + j];
                    if (c == ccur) {
                        sv += v;
                    } else {
                        const int slot = ccur - colbase;
                        if (slot < NSLOT) {
                            if (sv != 0.f) atomicAdd(&lacc[slot * OC + c2], sv);
                        } else {
                            if (sv != 0.f) atomicAdd(&out[(size_t)ccur * OC + c2], sv);
                        }
                        ccur = c; sv = v;
                    }
                }
                const int slot = ccur - colbase;
                if (slot < NSLOT) {
                    if (sv != 0.f) atomicAdd(&lacc[slot * OC + c2], sv);
                } else {
                    if (sv != 0.f) atomicAdd(&out[(size_t)ccur * OC + c2], sv);
                }
            }
        }
        // eaL(ii+1) <- prefetched regs (waits vmcnt for pA here, ~2000cy old)
        eaL[(cb ^ 1) * 256 + ((em * 4 + q) ^ esz)] = pA;
        BAR();  // BAR-2: lacc complete + eaL(ii+1) visible

        // ======== flush lacc -> out + self-zero ==========================
        int span = scolL[ib4 * 64 + EPB - 1] - colbase + 1;
        if (span > NSLOT) span = NSLOT;
        for (int idx = t; idx < span * OC; idx += NT) {
            const float v = lacc[idx];
            lacc[idx] = 0.f;
            if (v != 0.f)
                atomicAdd(&out[(size_t)(colbase + (idx >> 7)) * OC + (idx & 127)], v);
        }
    }
}

#define LDS_BYTES 55296

extern "C" void kernel_launch(void* const* d_in, const int* in_sizes, int n_in,
                              void* d_out, int out_size, void* d_ws, size_t ws_size,
                              hipStream_t stream) {
    const float* x    = (const float*)d_in[0];
    const int*   eidx = (const int*)d_in[1];
    const float* ea   = (const float*)d_in[2];
    const float* W1   = (const float*)d_in[3];
    const float* b1   = (const float*)d_in[4];
    const float* W2   = (const float*)d_in[5];
    const float* b2   = (const float*)d_in[6];
    float* out = (float*)d_out;

    const int E = in_sizes[1] / 2;

    char* ws = (char*)d_ws;
    float* xw1b    = (float*)ws;                         // 2 MB
    int*   hist8   = (int*)(ws + 2097152);               // 128 KB
    int*   cursor8 = (int*)(ws + 2097152 + 131072);      // 128 KB
    int2*  csr     = (int2*)(ws + 2097152 + 262144);     // 2 MB

    hipMemsetAsync(hist8, 0, 131072, stream);
    k_xw1<<<NN / 8, 128, 0, stream>>>(x, W1, b1, eidx, xw1b, out, hist8, E);
    k_scan<<<1, 256, 0, stream>>>(hist8, cursor8);
    k_scatter<<<(E + 255) / 256, 256, 0, stream>>>(eidx, cursor8, csr, E);

    hipFuncSetAttribute(reinterpret_cast<const void*>(k_edge9),
                        hipFuncAttributeMaxDynamicSharedMemorySize, LDS_BYTES);
    k_edge9<<<NBLK, NT, LDS_BYTES, stream>>>(csr, ea, xw1b, W1, W2, b2, out, E);
}